// Round 12
// baseline (83.567 us; speedup 1.0000x reference)
//
#include <hip/hip_runtime.h>
#include <math.h>

#define SS 61
#define EPSV 1e-5f

typedef __attribute__((ext_vector_type(8))) short bf16x8;
typedef __attribute__((ext_vector_type(4))) short s16x4;
typedef __attribute__((ext_vector_type(4))) float f32x4;

__device__ __forceinline__ short f2bf(float f){
  return __builtin_bit_cast(short, (__bf16)f);
}
__device__ __forceinline__ float bf2f(short s){
  unsigned u = ((unsigned)(unsigned short)s) << 16;
  return __builtin_bit_cast(float, u);
}
__device__ __forceinline__ bf16x8 pack8(f32x4 lo, f32x4 hi){
  bf16x8 r;
  r[0]=f2bf(lo[0]); r[1]=f2bf(lo[1]); r[2]=f2bf(lo[2]); r[3]=f2bf(lo[3]);
  r[4]=f2bf(hi[0]); r[5]=f2bf(hi[1]); r[6]=f2bf(hi[2]); r[7]=f2bf(hi[3]);
  return r;
}
__device__ __forceinline__ s16x4 pack4(f32x4 v){
  s16x4 r; r[0]=f2bf(v[0]); r[1]=f2bf(v[1]); r[2]=f2bf(v[2]); r[3]=f2bf(v[3]); return r;
}
// xformer swizzles (verified R3-R6)
#define YI(t,d) (((t)<<7) + ((d) ^ (((t)&7)<<2)))
#define OI(t,e) (((t)<<7) + ((e) ^ (((t)&7)<<2)))
#define FI(t,e) (((t)<<8) + ((e) ^ (((t)&7)<<2)))
#define VI(k,d) (((k)<<5) + ((d) ^ (((k)&7)<<2)))

// ================= weight prep: fp32 -> bf16 fragment-linear (unchanged) ====
__global__ __launch_bounds__(256) void prep_kernel(
    const float* __restrict__ ew1, const float* __restrict__ eb1,
    const float* __restrict__ ew2, const float* __restrict__ ew3,
    const float* __restrict__ in_w, const float* __restrict__ ow,
    const float* __restrict__ f1w, const float* __restrict__ f2w,
    const float* __restrict__ fc1w, const float* __restrict__ fc15w,
    const float* __restrict__ fc2w, const float* __restrict__ fcw,
    unsigned short* __restrict__ wbf)
{
  int s = blockIdx.x * 256 + threadIdx.x;
  int i = s & 7, lane = (s >> 3) & 63, frag = s >> 9;
  int c = lane & 15, g = lane >> 4;
  int sig = 16 * (i >> 2) + 4 * g + (i & 3);
  unsigned short outv;
  if (frag < 8) {
    int mt = frag & 3;
    float base = (sig < 3) ? ew1[sig * 64 + 16 * mt + c]
               : (sig == 3 ? eb1[16 * mt + c] : 0.f);
    short hv = f2bf(base);
    if (frag < 4) outv = (unsigned short)hv;
    else { float rv = base - bf2f(hv); outv = (unsigned short)f2bf(rv); }
  } else if (frag < 24) {
    int f = frag - 8; int mt = f >> 1, ks = f & 1;
    outv = (unsigned short)f2bf(ew2[(32 * ks + sig) * 128 + 16 * mt + c]);
  } else if (frag < 56) {
    int f = frag - 24; int mt = f >> 2, ks = f & 3;
    outv = (unsigned short)f2bf(ew3[(32 * ks + sig) * 128 + 16 * mt + c]);
  } else if (frag < 568) {
    int f = frag - 56; int l = f >> 8; f &= 255;
    float v;
    if (f < 96) { int tq = f >> 2, ks = f & 3;
      v = in_w[(size_t)l * 49152 + (size_t)(16 * tq + c) * 128 + 32 * ks + sig]; }
    else if (f < 128) { int f3 = f - 96; int t = f3 >> 2, ks = f3 & 3;
      v = ow[(size_t)l * 16384 + (size_t)(16 * t + c) * 128 + 32 * ks + sig]; }
    else if (f < 192) { int f3 = f - 128; int t = f3 >> 2, ks = f3 & 3;
      v = f1w[(size_t)l * 32768 + (size_t)(16 * t + c) * 128 + 32 * ks + sig]; }
    else { int f3 = f - 192; int t = f3 >> 3, ks = f3 & 7;
      v = f2w[(size_t)l * 32768 + (size_t)(16 * t + c) * 256 + 32 * ks + sig]; }
    outv = (unsigned short)f2bf(v);
  } else {
    int f = frag - 568;
    float v; int hl;
    if (f < 128) { hl = f >> 6; int f6 = f & 63; int mt = f6 >> 3, ks = f6 & 7;
      v = fc1w[(32 * ks + sig) * 128 + 16 * mt + c]; }
    else if (f < 160) { int f2_ = f - 128; hl = f2_ >> 4; int f4 = f2_ & 15; int mt = f4 >> 2, ks = f4 & 3;
      v = fc15w[(32 * ks + sig) * 64 + 16 * mt + c]; }
    else if (f < 168) { int f2_ = f - 160; hl = f2_ >> 2; int f4 = f2_ & 3; int mt = f4 >> 1, ks = f4 & 1;
      v = fc2w[(32 * ks + sig) * 32 + 16 * mt + c]; }
    else { int f2_ = f - 168; hl = f2_ >> 1; int mt = f2_ & 1; int m = 16 * mt + c;
      v = (m < 27) ? fcw[sig * 27 + m] : 0.f; }
    short hv = f2bf(v);
    outv = hl ? (unsigned short)f2bf(v - bf2f(hv)) : (unsigned short)hv;
  }
  wbf[s] = outv;
}

// ====== encoder v6: producer/consumer wave pairs, 2 waves/SIMD ======
// Pair p (frame blockIdx*4+p): wave 2p = PRODUCER (A1+A2, L1+L2 -> LDS h2),
// wave 2p+1 = CONSUMER (A3, L3 + max-pool), lagging one iteration.
// LDS exchange uses the v3c-verified sigma slot-order + XOR swizzle + swap8.
__global__ __launch_bounds__(512, 2) void enc_kernel(
    const float* __restrict__ x,
    const float* __restrict__ eb2, const float* __restrict__ eb3,
    const unsigned short* __restrict__ wbf,
    float* __restrict__ ymax)
{
  __shared__ __align__(16) unsigned short h2x[4][2][2][32][64]; // [pair][buf][half][pt][64] 64KB
  const int tid = threadIdx.x, lane = tid & 63, wv = tid >> 6;
  const int c = lane & 15, g = lane >> 4;
  const int pair = wv >> 1, role = wv & 1;
  const int frame = blockIdx.x * 4 + pair;
  const bf16x8* wf = (const bf16x8*)wbf;
  const int swap8 = c >> 3;

  if (role == 0) {
    // ---------------- PRODUCER: L1 (hi/lo) + L2 ----------------
    bf16x8 A1h[4], A1l[4];
#pragma unroll
    for (int mt = 0; mt < 4; mt++) { A1h[mt] = wf[mt * 64 + lane]; A1l[mt] = wf[(4 + mt) * 64 + lane]; }
    bf16x8 A2f[8][2];
#pragma unroll
    for (int mt = 0; mt < 8; mt++)
#pragma unroll
      for (int ks = 0; ks < 2; ks++) A2f[mt][ks] = wf[(8 + mt * 2 + ks) * 64 + lane];
    f32x4 b2v[8];
#pragma unroll
    for (int mt = 0; mt < 8; mt++) b2v[mt] = *(const f32x4*)(eb2 + 16 * mt + 4 * g);

    const float* xf = x + (size_t)frame * 1536;
    float nx[2][3];
#pragma unroll
    for (int nt = 0; nt < 2; nt++) {
      const float* xp = xf + (16 * nt + c) * 3;
      nx[nt][0] = xp[0]; nx[nt][1] = xp[1]; nx[nt][2] = xp[2];
    }

    for (int t = 0; t <= 16; t++) {
      __syncthreads();
      if (t >= 16) continue;
      float cx[2][3];
#pragma unroll
      for (int nt = 0; nt < 2; nt++) {
        cx[nt][0] = nx[nt][0]; cx[nt][1] = nx[nt][1]; cx[nt][2] = nx[nt][2];
      }
      if (t < 15) {
#pragma unroll
        for (int nt = 0; nt < 2; nt++) {
          const float* xp = xf + ((t + 1) * 32 + 16 * nt + c) * 3;
          nx[nt][0] = xp[0]; nx[nt][1] = xp[1]; nx[nt][2] = xp[2];
        }
      }
#pragma unroll
      for (int nt = 0; nt < 2; nt++) {
        bf16x8 bxh = {0,0,0,0,0,0,0,0}, bxl = {0,0,0,0,0,0,0,0};
        if (g == 0) {
          short h0 = f2bf(cx[nt][0]), h1_ = f2bf(cx[nt][1]), h2_ = f2bf(cx[nt][2]);
          bxh[0] = h0; bxh[1] = h1_; bxh[2] = h2_; bxh[3] = (short)0x3F80;
          bxl[0] = f2bf(cx[nt][0] - bf2f(h0));
          bxl[1] = f2bf(cx[nt][1] - bf2f(h1_));
          bxl[2] = f2bf(cx[nt][2] - bf2f(h2_));
        }
        f32x4 d1[4];
#pragma unroll
        for (int mt = 0; mt < 4; mt++) {
          f32x4 a = {0.f, 0.f, 0.f, 0.f};
          a = __builtin_amdgcn_mfma_f32_16x16x32_bf16(A1h[mt], bxh, a, 0, 0, 0);
          a = __builtin_amdgcn_mfma_f32_16x16x32_bf16(A1h[mt], bxl, a, 0, 0, 0);
          a = __builtin_amdgcn_mfma_f32_16x16x32_bf16(A1l[mt], bxh, a, 0, 0, 0);
          d1[mt] = a;
        }
        bf16x8 B2[2];
#pragma unroll
        for (int ks = 0; ks < 2; ks++) {
          bf16x8 r;
#pragma unroll
          for (int i = 0; i < 8; i++)
            r[i] = f2bf(fmaxf(d1[2 * ks + (i >> 2)][i & 3], 0.f));
          B2[ks] = r;
        }
        const int pt = 16 * nt + c;
#pragma unroll
        for (int mt = 0; mt < 8; mt++) {
          f32x4 a = b2v[mt];
          a = __builtin_amdgcn_mfma_f32_16x16x32_bf16(A2f[mt][0], B2[0], a, 0, 0, 0);
          a = __builtin_amdgcn_mfma_f32_16x16x32_bf16(A2f[mt][1], B2[1], a, 0, 0, 0);
          f32x4 rl;
#pragma unroll
          for (int r = 0; r < 4; r++) rl[r] = fmaxf(a[r], 0.f);
          const int half = mt >> 2, j = mt & 3;
          unsigned short* hb = &h2x[pair][t & 1][half][0][0];
          const int idx2 = ((j >> 1) * 32 + g * 8 + (j & 1) * 4) * 2;
          const int off = (idx2 ^ ((pt & 7) << 4)) ^ (swap8 << 3);
          *(s16x4*)((char*)hb + pt * 128 + off) = pack4(rl);
        }
      }
    }
  } else {
    // ---------------- CONSUMER: L3 + max-pool ----------------
    bf16x8 A3f[8][4];
#pragma unroll
    for (int mt = 0; mt < 8; mt++)
#pragma unroll
      for (int ks = 0; ks < 4; ks++) A3f[mt][ks] = wf[(24 + mt * 4 + ks) * 64 + lane];
    f32x4 pool[8];
#pragma unroll
    for (int mt = 0; mt < 8; mt++) pool[mt] = {-1e30f, -1e30f, -1e30f, -1e30f};

    for (int t = 0; t <= 16; t++) {
      __syncthreads();
      if (t == 0) continue;
      const int tb = (t - 1) & 1;
#pragma unroll
      for (int nt = 0; nt < 2; nt++) {
        const int pt = 16 * nt + c;
        bf16x8 Bx[4];
#pragma unroll
        for (int half = 0; half < 2; half++)
#pragma unroll
          for (int ksl = 0; ksl < 2; ksl++) {
            const unsigned short* hb = &h2x[pair][tb][half][0][0];
            const int off = (64 * ksl + 16 * g) ^ ((pt & 7) << 4);
            bf16x8 v = *(const bf16x8*)((const char*)hb + pt * 128 + off);
            bf16x8 vs = __builtin_shufflevector(v, v, 4, 5, 6, 7, 0, 1, 2, 3);
            Bx[2 * half + ksl] = swap8 ? vs : v;
          }
#pragma unroll
        for (int mt = 0; mt < 8; mt++) {
          f32x4 a = {0.f, 0.f, 0.f, 0.f};
          a = __builtin_amdgcn_mfma_f32_16x16x32_bf16(A3f[mt][0], Bx[0], a, 0, 0, 0);
          a = __builtin_amdgcn_mfma_f32_16x16x32_bf16(A3f[mt][1], Bx[1], a, 0, 0, 0);
          a = __builtin_amdgcn_mfma_f32_16x16x32_bf16(A3f[mt][2], Bx[2], a, 0, 0, 0);
          a = __builtin_amdgcn_mfma_f32_16x16x32_bf16(A3f[mt][3], Bx[3], a, 0, 0, 0);
#pragma unroll
          for (int r = 0; r < 4; r++) pool[mt][r] = fmaxf(pool[mt][r], a[r]);
        }
      }
    }

    // reduce over 16 point-columns, write out
#pragma unroll
    for (int mt = 0; mt < 8; mt++)
#pragma unroll
      for (int r = 0; r < 4; r++) {
        float v = pool[mt][r];
        v = fmaxf(v, __shfl_xor(v, 1, 64));
        v = fmaxf(v, __shfl_xor(v, 2, 64));
        v = fmaxf(v, __shfl_xor(v, 4, 64));
        v = fmaxf(v, __shfl_xor(v, 8, 64));
        pool[mt][r] = v;
      }
    if (c == 0) {
#pragma unroll
      for (int mt = 0; mt < 8; mt++)
#pragma unroll
        for (int r = 0; r < 4; r++) {
          const int ch = 16 * mt + 4 * g + r;
          ymax[(size_t)frame * 128 + ch] = pool[mt][r] + eb3[ch];
        }
    }
  }
}

// ====== fused transformer: 1 block/batch, 512 threads, in-phase W loads (R6) ======
__global__ __launch_bounds__(512, 1) void xformer_kernel(
    const float* __restrict__ ymax, const int* __restrict__ fl,
    const float* __restrict__ ctok, const float* __restrict__ cpos,
    const unsigned short* __restrict__ wbf,
    const float* __restrict__ in_b, const float* __restrict__ ob,
    const float* __restrict__ l1g, const float* __restrict__ l1b,
    const float* __restrict__ f1b, const float* __restrict__ f2b,
    const float* __restrict__ l2g, const float* __restrict__ l2b,
    float* __restrict__ zbuf)
{
  __shared__ __align__(16) float ylds[64 * 128];
  __shared__ __align__(16) unsigned short ubuf[64 * 256];
  __shared__ __align__(16) unsigned short kq4[2][8][4][64][4];
  const int b = blockIdx.x, tid = threadIdx.x;
  const int w8 = tid >> 6, lane = tid & 63, c = lane & 15, g = lane >> 4;
  const int h = w8 >> 1, sub = w8 & 1;
  const int flb = fl[b];
  const float scl = 0.17677669529663687f;

  for (int it = 0; it < 16; it++) {
    int idx = it * 512 + tid;
    int t = idx >> 7, d = idx & 127;
    float v;
    if (t == 0) v = ctok[d] + cpos[d];
    else if (t <= 60) {
      int f = t - 1;
      float ym = (f < flb) ? ymax[(size_t)(b * 60 + f) * 128 + d] : 0.f;
      float dv = __expf((float)(d & ~1) * (-0.07195578416f));
      float ang = (float)f * dv;
      v = ym + ((d & 1) ? __cosf(ang) : __sinf(ang));
    } else v = 0.f;
    ylds[YI(t, d)] = v;
  }
  __syncthreads();

  for (int l = 0; l < 2; l++) {
    const unsigned short* WL = wbf + 28672 + (size_t)l * 131072;
    const bf16x8* wq  = (const bf16x8*)WL;
    const bf16x8* wo  = (const bf16x8*)(WL + 49152);
    const bf16x8* w1p = (const bf16x8*)(WL + 65536);
    const bf16x8* w2p = (const bf16x8*)(WL + 98304);
    unsigned short* vb = ubuf + 8192 + h * 2048;

    // ---------- qkv ----------
    {
      bf16x8 yB[4][4];
#pragma unroll
      for (int nt = 0; nt < 4; nt++)
#pragma unroll
        for (int ks = 0; ks < 4; ks++) {
          f32x4 lo = *(const f32x4*)&ylds[YI(16 * nt + c, 32 * ks + 4 * g)];
          f32x4 hi = *(const f32x4*)&ylds[YI(16 * nt + c, 32 * ks + 16 + 4 * g)];
          yB[nt][ks] = pack8(lo, hi);
        }
#pragma unroll
      for (int p = 0; p < 3; p++) {
        const int tq = p * 8 + w8;
        bf16x8 Af[4];
#pragma unroll
        for (int ks = 0; ks < 4; ks++) Af[ks] = wq[(tq * 4 + ks) * 64 + lane];
        f32x4 bias = *(const f32x4*)(in_b + l * 384 + p * 128 + 16 * w8 + 4 * g);
        f32x4 acc[4];
#pragma unroll
        for (int nt = 0; nt < 4; nt++) acc[nt] = bias;
#pragma unroll
        for (int ks = 0; ks < 4; ks++)
#pragma unroll
          for (int nt = 0; nt < 4; nt++)
            acc[nt] = __builtin_amdgcn_mfma_f32_16x16x32_bf16(Af[ks], yB[nt][ks], acc[nt], 0, 0, 0);
        if (p == 2) {
#pragma unroll
          for (int nt = 0; nt < 4; nt++)
            *(s16x4*)&vb[VI(16 * nt + c, 16 * sub + 4 * g)] = pack4(acc[nt]);
        } else {
#pragma unroll
          for (int nt = 0; nt < 4; nt++) {
            f32x4 sv = acc[nt];
            if (p == 0) sv = sv * scl;
            *(s16x4*)&kq4[p][w8][nt][lane][0] = pack4(sv);
          }
        }
      }
    }
    __syncthreads();

    // ---------- attention ----------
    {
      bf16x8 Ak[4], Bq2[2];
#pragma unroll
      for (int kt = 0; kt < 4; kt++) {
        s16x4 lo = *(const s16x4*)&kq4[1][2 * h][kt][lane][0];
        s16x4 hi = *(const s16x4*)&kq4[1][2 * h + 1][kt][lane][0];
        Ak[kt] = __builtin_shufflevector(lo, hi, 0, 1, 2, 3, 4, 5, 6, 7);
      }
#pragma unroll
      for (int j = 0; j < 2; j++) {
        s16x4 lo = *(const s16x4*)&kq4[0][2 * h][2 * sub + j][lane][0];
        s16x4 hi = *(const s16x4*)&kq4[0][2 * h + 1][2 * sub + j][lane][0];
        Bq2[j] = __builtin_shufflevector(lo, hi, 0, 1, 2, 3, 4, 5, 6, 7);
      }
      f32x4 St[4][2];
#pragma unroll
      for (int kt = 0; kt < 4; kt++)
#pragma unroll
        for (int j = 0; j < 2; j++) {
          f32x4 z = {0.f, 0.f, 0.f, 0.f};
          St[kt][j] = __builtin_amdgcn_mfma_f32_16x16x32_bf16(Ak[kt], Bq2[j], z, 0, 0, 0);
        }
#pragma unroll
      for (int j = 0; j < 2; j++) {
        float m = -1e30f;
#pragma unroll
        for (int kt = 0; kt < 4; kt++)
#pragma unroll
          for (int r = 0; r < 4; r++) {
            const int kp = 16 * kt + 4 * g + r;
            float s = St[kt][j][r];
            s = (kp > flb) ? -1e30f : s;
            St[kt][j][r] = s;
            m = fmaxf(m, s);
          }
        m = fmaxf(m, __shfl_xor(m, 16, 64));
        m = fmaxf(m, __shfl_xor(m, 32, 64));
        float sum = 0.f;
#pragma unroll
        for (int kt = 0; kt < 4; kt++)
#pragma unroll
          for (int r = 0; r < 4; r++) {
            float p = __expf(St[kt][j][r] - m);
            St[kt][j][r] = p;
            sum += p;
          }
        sum += __shfl_xor(sum, 16, 64);
        sum += __shfl_xor(sum, 32, 64);
        const float inv = 1.f / sum;
#pragma unroll
        for (int kt = 0; kt < 4; kt++)
#pragma unroll
          for (int r = 0; r < 4; r++) St[kt][j][r] *= inv;
      }
      bf16x8 Bp[2][2];
#pragma unroll
      for (int j = 0; j < 2; j++)
#pragma unroll
        for (int ks = 0; ks < 2; ks++) {
          bf16x8 r;
#pragma unroll
          for (int i = 0; i < 8; i++) r[i] = f2bf(St[2 * ks + (i >> 2)][j][i & 3]);
          Bp[j][ks] = r;
        }
      bf16x8 Av[2][2];
#pragma unroll
      for (int dt = 0; dt < 2; dt++)
#pragma unroll
        for (int ks = 0; ks < 2; ks++) {
          bf16x8 r;
#pragma unroll
          for (int i = 0; i < 8; i++) {
            const int kp = 32 * ks + 16 * (i >> 2) + 4 * g + (i & 3);
            r[i] = (short)vb[VI(kp, 16 * dt + c)];
          }
          Av[dt][ks] = r;
        }
#pragma unroll
      for (int dt = 0; dt < 2; dt++)
#pragma unroll
        for (int j = 0; j < 2; j++) {
          f32x4 z = {0.f, 0.f, 0.f, 0.f};
          z = __builtin_amdgcn_mfma_f32_16x16x32_bf16(Av[dt][0], Bp[j][0], z, 0, 0, 0);
          z = __builtin_amdgcn_mfma_f32_16x16x32_bf16(Av[dt][1], Bp[j][1], z, 0, 0, 0);
          *(s16x4*)&ubuf[OI(16 * (2 * sub + j) + c, 32 * h + 16 * dt + 4 * g)] = pack4(z);
        }
    }
    __syncthreads();

    // ---------- proj + residual ----------
    {
      bf16x8 Bo[4][4];
#pragma unroll
      for (int nt = 0; nt < 4; nt++)
#pragma unroll
        for (int ks = 0; ks < 4; ks++) {
          s16x4 lo = *(const s16x4*)&ubuf[OI(16 * nt + c, 32 * ks + 4 * g)];
          s16x4 hi = *(const s16x4*)&ubuf[OI(16 * nt + c, 32 * ks + 16 + 4 * g)];
          Bo[nt][ks] = __builtin_shufflevector(lo, hi, 0, 1, 2, 3, 4, 5, 6, 7);
        }
      const int j0 = 16 * w8;
      bf16x8 Af[4];
#pragma unroll
      for (int ks = 0; ks < 4; ks++) Af[ks] = wo[(w8 * 4 + ks) * 64 + lane];
      f32x4 bias = *(const f32x4*)(ob + l * 128 + j0 + 4 * g);
      f32x4 acc[4];
#pragma unroll
      for (int nt = 0; nt < 4; nt++) acc[nt] = bias;
#pragma unroll
      for (int ks = 0; ks < 4; ks++)
#pragma unroll
        for (int nt = 0; nt < 4; nt++)
          acc[nt] = __builtin_amdgcn_mfma_f32_16x16x32_bf16(Af[ks], Bo[nt][ks], acc[nt], 0, 0, 0);
#pragma unroll
      for (int nt = 0; nt < 4; nt++) {
        float* yp = &ylds[YI(16 * nt + c, j0 + 4 * g)];
        *(f32x4*)yp = *(const f32x4*)yp + acc[nt];
      }
    }
    __syncthreads();
    // ---------- LN1 ----------
    {
      const int t = 8 * w8 + (lane >> 3);
      const int s = lane & 7;
      f32x4 vv[4];
      float s1 = 0.f, s2 = 0.f;
#pragma unroll
      for (int k = 0; k < 4; k++) {
        vv[k] = *(const f32x4*)&ylds[YI(t, s * 16 + 4 * k)];
#pragma unroll
        for (int r = 0; r < 4; r++) { s1 += vv[k][r]; s2 = fmaf(vv[k][r], vv[k][r], s2); }
      }
      s1 += __shfl_xor(s1, 1, 64); s1 += __shfl_xor(s1, 2, 64); s1 += __shfl_xor(s1, 4, 64);
      s2 += __shfl_xor(s2, 1, 64); s2 += __shfl_xor(s2, 2, 64); s2 += __shfl_xor(s2, 4, 64);
      const float mean = s1 * 0.0078125f;
      const float var  = s2 * 0.0078125f - mean * mean;
      const float inv  = rsqrtf(var + EPSV);
#pragma unroll
      for (int k = 0; k < 4; k++) {
        f32x4 gg = *(const f32x4*)(l1g + l * 128 + s * 16 + 4 * k);
        f32x4 bb = *(const f32x4*)(l1b + l * 128 + s * 16 + 4 * k);
        f32x4 o;
#pragma unroll
        for (int r = 0; r < 4; r++) o[r] = (vv[k][r] - mean) * inv * gg[r] + bb[r];
        *(f32x4*)&ylds[YI(t, s * 16 + 4 * k)] = o;
      }
    }
    __syncthreads();

    // ---------- ff1 (relu) ----------
    {
      bf16x8 yB[4][4];
#pragma unroll
      for (int nt = 0; nt < 4; nt++)
#pragma unroll
        for (int ks = 0; ks < 4; ks++) {
          f32x4 lo = *(const f32x4*)&ylds[YI(16 * nt + c, 32 * ks + 4 * g)];
          f32x4 hi = *(const f32x4*)&ylds[YI(16 * nt + c, 32 * ks + 16 + 4 * g)];
          yB[nt][ks] = pack8(lo, hi);
        }
#pragma unroll
      for (int half = 0; half < 2; half++) {
        const int t16 = 8 * half + w8;
        bf16x8 Af[4];
#pragma unroll
        for (int ks = 0; ks < 4; ks++) Af[ks] = w1p[(t16 * 4 + ks) * 64 + lane];
        f32x4 bias = *(const f32x4*)(f1b + l * 256 + 16 * t16 + 4 * g);
        f32x4 acc[4];
#pragma unroll
        for (int nt = 0; nt < 4; nt++) acc[nt] = bias;
#pragma unroll
        for (int ks = 0; ks < 4; ks++)
#pragma unroll
          for (int nt = 0; nt < 4; nt++)
            acc[nt] = __builtin_amdgcn_mfma_f32_16x16x32_bf16(Af[ks], yB[nt][ks], acc[nt], 0, 0, 0);
#pragma unroll
        for (int nt = 0; nt < 4; nt++) {
          f32x4 rl;
#pragma unroll
          for (int r = 0; r < 4; r++) rl[r] = fmaxf(acc[nt][r], 0.f);
          *(s16x4*)&ubuf[FI(16 * nt + c, 16 * t16 + 4 * g)] = pack4(rl);
        }
      }
    }
    __syncthreads();
    // ---------- ff2 + residual ----------
    {
      f32x4 acc[4];
      f32x4 bias = *(const f32x4*)(f2b + l * 128 + 16 * w8 + 4 * g);
#pragma unroll
      for (int nt = 0; nt < 4; nt++) acc[nt] = bias;
#pragma unroll
      for (int ks = 0; ks < 8; ks++) {
        bf16x8 Af = w2p[(w8 * 8 + ks) * 64 + lane];
        bf16x8 Bf[4];
#pragma unroll
        for (int nt = 0; nt < 4; nt++) {
          s16x4 lo = *(const s16x4*)&ubuf[FI(16 * nt + c, 32 * ks + 4 * g)];
          s16x4 hi = *(const s16x4*)&ubuf[FI(16 * nt + c, 32 * ks + 16 + 4 * g)];
          Bf[nt] = __builtin_shufflevector(lo, hi, 0, 1, 2, 3, 4, 5, 6, 7);
        }
#pragma unroll
        for (int nt = 0; nt < 4; nt++)
          acc[nt] = __builtin_amdgcn_mfma_f32_16x16x32_bf16(Af, Bf[nt], acc[nt], 0, 0, 0);
      }
#pragma unroll
      for (int nt = 0; nt < 4; nt++) {
        float* yp = &ylds[YI(16 * nt + c, 16 * w8 + 4 * g)];
        *(f32x4*)yp = *(const f32x4*)yp + acc[nt];
      }
    }
    __syncthreads();
    // ---------- LN2 ----------
    {
      const int t = 8 * w8 + (lane >> 3);
      const int s = lane & 7;
      f32x4 vv[4];
      float s1 = 0.f, s2 = 0.f;
#pragma unroll
      for (int k = 0; k < 4; k++) {
        vv[k] = *(const f32x4*)&ylds[YI(t, s * 16 + 4 * k)];
#pragma unroll
        for (int r = 0; r < 4; r++) { s1 += vv[k][r]; s2 = fmaf(vv[k][r], vv[k][r], s2); }
      }
      s1 += __shfl_xor(s1, 1, 64); s1 += __shfl_xor(s1, 2, 64); s1 += __shfl_xor(s1, 4, 64);
      s2 += __shfl_xor(s2, 1, 64); s2 += __shfl_xor(s2, 2, 64); s2 += __shfl_xor(s2, 4, 64);
      const float mean = s1 * 0.0078125f;
      const float var  = s2 * 0.0078125f - mean * mean;
      const float inv  = rsqrtf(var + EPSV);
#pragma unroll
      for (int k = 0; k < 4; k++) {
        f32x4 gg = *(const f32x4*)(l2g + l * 128 + s * 16 + 4 * k);
        f32x4 bb = *(const f32x4*)(l2b + l * 128 + s * 16 + 4 * k);
        f32x4 o;
#pragma unroll
        for (int r = 0; r < 4; r++) o[r] = (vv[k][r] - mean) * inv * gg[r] + bb[r];
        *(f32x4*)&ylds[YI(t, s * 16 + 4 * k)] = o;
      }
    }
    __syncthreads();
  }

  // classifier inputs, TRANSPOSED: zbuf[ch][b]
  if (tid < 256) {
    const int d = tid;
    float v = (d < 128) ? ylds[YI(0, d)] : ylds[YI(flb, d - 128)];
    zbuf[d * 16 + b] = v;
  }
}

// ====== head: MFMA hi/lo (≈fp32), transposed D[ch][batch], live BN (R6) ======
__device__ __forceinline__ void buildB(const float* src, int ks, int g, int c,
                                       bf16x8& bh, bf16x8& bl){
#pragma unroll
  for (int i = 0; i < 8; i++) {
    int k = 32 * ks + 16 * (i >> 2) + 4 * g + (i & 3);
    float v = src[k * 16 + c];
    short hv = f2bf(v);
    bh[i] = hv; bl[i] = f2bf(v - bf2f(hv));
  }
}
__device__ __forceinline__ void bn_lrelu_store(f32x4 acc, int ch0, int c,
    const float* __restrict__ gg, const float* __restrict__ bb, float* dst){
#pragma unroll
  for (int r = 0; r < 4; r++) {
    float v = acc[r];
    float s1 = v, s2 = v * v;
    s1 += __shfl_xor(s1, 1, 64); s2 += __shfl_xor(s2, 1, 64);
    s1 += __shfl_xor(s1, 2, 64); s2 += __shfl_xor(s2, 2, 64);
    s1 += __shfl_xor(s1, 4, 64); s2 += __shfl_xor(s2, 4, 64);
    s1 += __shfl_xor(s1, 8, 64); s2 += __shfl_xor(s2, 8, 64);
    const float m = s1 * (1.f / 16.f);
    const float var = s2 * (1.f / 16.f) - m * m;
    const float scl = gg[ch0 + r] / sqrtf(var + EPSV);
    const float sh = bb[ch0 + r] - m * scl;
    float o = v * scl + sh;
    o = (o > 0.f) ? o : 0.2f * o;
    dst[(ch0 + r) * 16 + c] = o;
  }
}

__global__ __launch_bounds__(256, 1) void head_kernel(
    const float* __restrict__ zt, const unsigned short* __restrict__ wbf,
    const float* __restrict__ fc1b, const float* __restrict__ bn1g, const float* __restrict__ bn1b,
    const float* __restrict__ fc15b, const float* __restrict__ bn15g, const float* __restrict__ bn15b,
    const float* __restrict__ fc2b, const float* __restrict__ bn2g, const float* __restrict__ bn2b,
    const float* __restrict__ fcb, float* __restrict__ out)
{
  __shared__ float zs[256 * 16];
  __shared__ float t1s[128 * 16];
  __shared__ float t15s[64 * 16];
  __shared__ float t2s[32 * 16];
  const int tid = threadIdx.x, lane = tid & 63, wv = tid >> 6;
  const int c = lane & 15, g = lane >> 4;
  const bf16x8* wf = (const bf16x8*)wbf;

  for (int idx = tid; idx < 4096; idx += 256) zs[idx] = zt[idx];
  __syncthreads();

  {
    f32x4 acc[2];
#pragma unroll
    for (int j = 0; j < 2; j++) {
      const int ch0 = 16 * (2 * wv + j) + 4 * g;
      f32x4 a;
#pragma unroll
      for (int r = 0; r < 4; r++) a[r] = fc1b[ch0 + r];
      acc[j] = a;
    }
#pragma unroll
    for (int ks = 0; ks < 8; ks++) {
      bf16x8 bh, bl; buildB(zs, ks, g, c, bh, bl);
#pragma unroll
      for (int j = 0; j < 2; j++) {
        const int mt = 2 * wv + j;
        bf16x8 Ah = wf[(568 + mt * 8 + ks) * 64 + lane];
        bf16x8 Al = wf[(632 + mt * 8 + ks) * 64 + lane];
        acc[j] = __builtin_amdgcn_mfma_f32_16x16x32_bf16(Ah, bh, acc[j], 0, 0, 0);
        acc[j] = __builtin_amdgcn_mfma_f32_16x16x32_bf16(Ah, bl, acc[j], 0, 0, 0);
        acc[j] = __builtin_amdgcn_mfma_f32_16x16x32_bf16(Al, bh, acc[j], 0, 0, 0);
      }
    }
#pragma unroll
    for (int j = 0; j < 2; j++)
      bn_lrelu_store(acc[j], 16 * (2 * wv + j) + 4 * g, c, bn1g, bn1b, t1s);
  }
  __syncthreads();

  {
    const int ch0 = 16 * wv + 4 * g;
    f32x4 a;
#pragma unroll
    for (int r = 0; r < 4; r++) a[r] = fc15b[ch0 + r];
#pragma unroll
    for (int ks = 0; ks < 4; ks++) {
      bf16x8 bh, bl; buildB(t1s, ks, g, c, bh, bl);
      bf16x8 Ah = wf[(696 + wv * 4 + ks) * 64 + lane];
      bf16x8 Al = wf[(712 + wv * 4 + ks) * 64 + lane];
      a = __builtin_amdgcn_mfma_f32_16x16x32_bf16(Ah, bh, a, 0, 0, 0);
      a = __builtin_amdgcn_mfma_f32_16x16x32_bf16(Ah, bl, a, 0, 0, 0);
      a = __builtin_amdgcn_mfma_f32_16x16x32_bf16(Al, bh, a, 0, 0, 0);
    }
    bn_lrelu_store(a, ch0, c, bn15g, bn15b, t15s);
  }
  __syncthreads();

  if (wv < 2) {
    const int ch0 = 16 * wv + 4 * g;
    f32x4 a;
#pragma unroll
    for (int r = 0; r < 4; r++) a[r] = fc2b[ch0 + r];
#pragma unroll
    for (int ks = 0; ks < 2; ks++) {
      bf16x8 bh, bl; buildB(t15s, ks, g, c, bh, bl);
      bf16x8 Ah = wf[(728 + wv * 2 + ks) * 64 + lane];
      bf16x8 Al = wf[(732 + wv * 2 + ks) * 64 + lane];
      a = __builtin_amdgcn_mfma_f32_16x16x32_bf16(Ah, bh, a, 0, 0, 0);
      a = __builtin_amdgcn_mfma_f32_16x16x32_bf16(Ah, bl, a, 0, 0, 0);
      a = __builtin_amdgcn_mfma_f32_16x16x32_bf16(Al, bh, a, 0, 0, 0);
    }
    bn_lrelu_store(a, ch0, c, bn2g, bn2b, t2s);
  }
  __syncthreads();

  if (wv < 2) {
    f32x4 a;
#pragma unroll
    for (int r = 0; r < 4; r++) {
      const int ch = 16 * wv + 4 * g + r;
      a[r] = (ch < 27) ? fcb[ch] : 0.f;
    }
    bf16x8 bh, bl; buildB(t2s, 0, g, c, bh, bl);
    bf16x8 Ah = wf[(736 + wv) * 64 + lane];
    bf16x8 Al = wf[(738 + wv) * 64 + lane];
    a = __builtin_amdgcn_mfma_f32_16x16x32_bf16(Ah, bh, a, 0, 0, 0);
    a = __builtin_amdgcn_mfma_f32_16x16x32_bf16(Ah, bl, a, 0, 0, 0);
    a = __builtin_amdgcn_mfma_f32_16x16x32_bf16(Al, bh, a, 0, 0, 0);
#pragma unroll
    for (int r = 0; r < 4; r++) {
      const int ch = 16 * wv + 4 * g + r;
      if (ch < 27) out[c * 27 + ch] = a[r];
    }
  }
}

extern "C" void kernel_launch(void* const* d_in, const int* in_sizes, int n_in,
                              void* d_out, int out_size, void* d_ws, size_t ws_size,
                              hipStream_t stream)
{
  const float* x    = (const float*)d_in[0];
  const int*   fl   = (const int*)d_in[1];
  const float* ew1  = (const float*)d_in[2];  const float* eb1 = (const float*)d_in[3];
  const float* ew2  = (const float*)d_in[4];  const float* eb2 = (const float*)d_in[5];
  const float* ew3  = (const float*)d_in[6];  const float* eb3 = (const float*)d_in[7];
  const float* ctok = (const float*)d_in[8];  const float* cpos = (const float*)d_in[9];
  const float* in_w = (const float*)d_in[10]; const float* in_b = (const float*)d_in[11];
  const float* ow   = (const float*)d_in[12]; const float* ob   = (const float*)d_in[13];
  const float* l1g  = (const float*)d_in[14]; const float* l1b  = (const float*)d_in[15];
  const float* f1w  = (const float*)d_in[16]; const float* f1b  = (const float*)d_in[17];
  const float* f2w  = (const float*)d_in[18]; const float* f2b  = (const float*)d_in[19];
  const float* l2g  = (const float*)d_in[20]; const float* l2b  = (const float*)d_in[21];
  const float* fc1w = (const float*)d_in[22]; const float* fc1b = (const float*)d_in[23];
  const float* bn1g = (const float*)d_in[24]; const float* bn1b = (const float*)d_in[25];
  const float* fc15w= (const float*)d_in[26]; const float* fc15b= (const float*)d_in[27];
  const float* bn15g= (const float*)d_in[28]; const float* bn15b= (const float*)d_in[29];
  const float* fc2w = (const float*)d_in[30]; const float* fc2b = (const float*)d_in[31];
  const float* bn2g = (const float*)d_in[32]; const float* bn2b = (const float*)d_in[33];
  const float* fcw  = (const float*)d_in[34]; const float* fcb  = (const float*)d_in[35];
  float* out = (float*)d_out;

  char* w = (char*)d_ws;
  float* ymax = (float*)w;                                   // 491520 B
  float* zbuf = (float*)(w + 491520);                        // 16384 B (transposed [ch][b])
  unsigned short* wbf = (unsigned short*)(w + 507904);       // 740 frags * 1024 B

  prep_kernel<<<1480, 256, 0, stream>>>(ew1, eb1, ew2, ew3, in_w, ow, f1w, f2w,
                                        fc1w, fc15w, fc2w, fcw, wbf);
  enc_kernel<<<240, 512, 0, stream>>>(x, eb2, eb3, wbf, ymax);
  xformer_kernel<<<16, 512, 0, stream>>>(ymax, fl, ctok, cpos, wbf, in_b, ob,
                                         l1g, l1b, f1b, f2b, l2g, l2b, zbuf);
  head_kernel<<<1, 256, 0, stream>>>(zbuf, wbf, fc1b, bn1g, bn1b,
                                     fc15b, bn15g, bn15b, fc2b, bn2g, bn2b, fcb, out);
}

// Round 13
// 77.756 us; speedup vs baseline: 1.0747x; 1.0747x over previous
//
#include <hip/hip_runtime.h>
#include <math.h>

#define SS 61
#define EPSV 1e-5f

typedef __attribute__((ext_vector_type(8))) short bf16x8;
typedef __attribute__((ext_vector_type(4))) short s16x4;
typedef __attribute__((ext_vector_type(4))) float f32x4;

__device__ __forceinline__ short f2bf(float f){
  return __builtin_bit_cast(short, (__bf16)f);
}
__device__ __forceinline__ float bf2f(short s){
  unsigned u = ((unsigned)(unsigned short)s) << 16;
  return __builtin_bit_cast(float, u);
}
__device__ __forceinline__ bf16x8 pack8(f32x4 lo, f32x4 hi){
  bf16x8 r;
  r[0]=f2bf(lo[0]); r[1]=f2bf(lo[1]); r[2]=f2bf(lo[2]); r[3]=f2bf(lo[3]);
  r[4]=f2bf(hi[0]); r[5]=f2bf(hi[1]); r[6]=f2bf(hi[2]); r[7]=f2bf(hi[3]);
  return r;
}
__device__ __forceinline__ s16x4 pack4(f32x4 v){
  s16x4 r; r[0]=f2bf(v[0]); r[1]=f2bf(v[1]); r[2]=f2bf(v[2]); r[3]=f2bf(v[3]); return r;
}
// xformer swizzles (verified R3-R6)
#define YI(t,d) (((t)<<7) + ((d) ^ (((t)&7)<<2)))
#define OI(t,e) (((t)<<7) + ((e) ^ (((t)&7)<<2)))
#define FI(t,e) (((t)<<8) + ((e) ^ (((t)&7)<<2)))
#define VI(k,d) (((k)<<5) + ((d) ^ (((k)&7)<<2)))

// ================= weight prep: fp32 -> bf16 fragment-linear (unchanged) ====
__global__ __launch_bounds__(256) void prep_kernel(
    const float* __restrict__ ew1, const float* __restrict__ eb1,
    const float* __restrict__ ew2, const float* __restrict__ ew3,
    const float* __restrict__ in_w, const float* __restrict__ ow,
    const float* __restrict__ f1w, const float* __restrict__ f2w,
    const float* __restrict__ fc1w, const float* __restrict__ fc15w,
    const float* __restrict__ fc2w, const float* __restrict__ fcw,
    unsigned short* __restrict__ wbf)
{
  int s = blockIdx.x * 256 + threadIdx.x;
  int i = s & 7, lane = (s >> 3) & 63, frag = s >> 9;
  int c = lane & 15, g = lane >> 4;
  int sig = 16 * (i >> 2) + 4 * g + (i & 3);
  unsigned short outv;
  if (frag < 8) {
    int mt = frag & 3;
    float base = (sig < 3) ? ew1[sig * 64 + 16 * mt + c]
               : (sig == 3 ? eb1[16 * mt + c] : 0.f);
    short hv = f2bf(base);
    if (frag < 4) outv = (unsigned short)hv;
    else { float rv = base - bf2f(hv); outv = (unsigned short)f2bf(rv); }
  } else if (frag < 24) {
    int f = frag - 8; int mt = f >> 1, ks = f & 1;
    outv = (unsigned short)f2bf(ew2[(32 * ks + sig) * 128 + 16 * mt + c]);
  } else if (frag < 56) {
    int f = frag - 24; int mt = f >> 2, ks = f & 3;
    outv = (unsigned short)f2bf(ew3[(32 * ks + sig) * 128 + 16 * mt + c]);
  } else if (frag < 568) {
    int f = frag - 56; int l = f >> 8; f &= 255;
    float v;
    if (f < 96) { int tq = f >> 2, ks = f & 3;
      v = in_w[(size_t)l * 49152 + (size_t)(16 * tq + c) * 128 + 32 * ks + sig]; }
    else if (f < 128) { int f3 = f - 96; int t = f3 >> 2, ks = f3 & 3;
      v = ow[(size_t)l * 16384 + (size_t)(16 * t + c) * 128 + 32 * ks + sig]; }
    else if (f < 192) { int f3 = f - 128; int t = f3 >> 2, ks = f3 & 3;
      v = f1w[(size_t)l * 32768 + (size_t)(16 * t + c) * 128 + 32 * ks + sig]; }
    else { int f3 = f - 192; int t = f3 >> 3, ks = f3 & 7;
      v = f2w[(size_t)l * 32768 + (size_t)(16 * t + c) * 256 + 32 * ks + sig]; }
    outv = (unsigned short)f2bf(v);
  } else {
    int f = frag - 568;
    float v; int hl;
    if (f < 128) { hl = f >> 6; int f6 = f & 63; int mt = f6 >> 3, ks = f6 & 7;
      v = fc1w[(32 * ks + sig) * 128 + 16 * mt + c]; }
    else if (f < 160) { int f2_ = f - 128; hl = f2_ >> 4; int f4 = f2_ & 15; int mt = f4 >> 2, ks = f4 & 3;
      v = fc15w[(32 * ks + sig) * 64 + 16 * mt + c]; }
    else if (f < 168) { int f2_ = f - 160; hl = f2_ >> 2; int f4 = f2_ & 3; int mt = f4 >> 1, ks = f4 & 1;
      v = fc2w[(32 * ks + sig) * 32 + 16 * mt + c]; }
    else { int f2_ = f - 168; hl = f2_ >> 1; int mt = f2_ & 1; int m = 16 * mt + c;
      v = (m < 27) ? fcw[sig * 27 + m] : 0.f; }
    short hv = f2bf(v);
    outv = hl ? (unsigned short)f2bf(v - bf2f(hv)) : (unsigned short)hv;
  }
  wbf[s] = outv;
}

// ====== encoder v7: barrier-free wave-per-frame; L1 on VALU (exact fp32), L2/L3 MFMA ======
// Each lane computes the 16 h1 channels its B2 fragment slots need:
// ch = 32ks + 16(i>>2) + 4g + (i&3)  (identity HW-verified since R2).
// Removes 12 of 60 MFMA slots/nt; L1 work runs on the VALU pipe concurrently.
__global__ __launch_bounds__(256, 1) void enc_kernel(
    const float* __restrict__ x,
    const float* __restrict__ ew1, const float* __restrict__ eb1,
    const float* __restrict__ eb2, const float* __restrict__ eb3,
    const unsigned short* __restrict__ wbf,
    float* __restrict__ ymax)
{
  const int tid = threadIdx.x, lane = tid & 63, wv = tid >> 6;
  const int c = lane & 15, g = lane >> 4;
  const int frame = blockIdx.x * 4 + wv;
  const bf16x8* wf = (const bf16x8*)wbf;

  // per-lane L1 weights (depend only on g; static register indices)
  float wa[2][8], wb_[2][8], wc_[2][8], b1v[2][8];
#pragma unroll
  for (int ks = 0; ks < 2; ks++)
#pragma unroll
    for (int i = 0; i < 8; i++) {
      const int ch = 32 * ks + 16 * (i >> 2) + 4 * g + (i & 3);
      wa[ks][i]  = ew1[ch];
      wb_[ks][i] = ew1[64 + ch];
      wc_[ks][i] = ew1[128 + ch];
      b1v[ks][i] = eb1[ch];
    }

  bf16x8 A2f[8][2];
#pragma unroll
  for (int mt = 0; mt < 8; mt++)
#pragma unroll
    for (int ks = 0; ks < 2; ks++) A2f[mt][ks] = wf[(8 + mt * 2 + ks) * 64 + lane];
  bf16x8 A3f[8][4];
#pragma unroll
  for (int mt = 0; mt < 8; mt++)
#pragma unroll
    for (int ks = 0; ks < 4; ks++) A3f[mt][ks] = wf[(24 + mt * 4 + ks) * 64 + lane];
  f32x4 b2v[8];
#pragma unroll
  for (int mt = 0; mt < 8; mt++) b2v[mt] = *(const f32x4*)(eb2 + 16 * mt + 4 * g);

  f32x4 pool[8];
#pragma unroll
  for (int mt = 0; mt < 8; mt++) pool[mt] = {-1e30f, -1e30f, -1e30f, -1e30f};

  const float* xf = x + (size_t)frame * 1536;
  float nx[2][3];
#pragma unroll
  for (int nt = 0; nt < 2; nt++) {
    const float* xp = xf + (16 * nt + c) * 3;
    nx[nt][0] = xp[0]; nx[nt][1] = xp[1]; nx[nt][2] = xp[2];
  }

  for (int t = 0; t < 16; t++) {
    float cx[2][3];
#pragma unroll
    for (int nt = 0; nt < 2; nt++) {
      cx[nt][0] = nx[nt][0]; cx[nt][1] = nx[nt][1]; cx[nt][2] = nx[nt][2];
    }
    if (t < 15) {
#pragma unroll
      for (int nt = 0; nt < 2; nt++) {
        const float* xp = xf + ((t + 1) * 32 + 16 * nt + c) * 3;
        nx[nt][0] = xp[0]; nx[nt][1] = xp[1]; nx[nt][2] = xp[2];
      }
    }
#pragma unroll
    for (int nt = 0; nt < 2; nt++) {
      // ---- L1 on VALU (exact fp32), pack straight into B2 fragments ----
      bf16x8 B2[2];
#pragma unroll
      for (int ks = 0; ks < 2; ks++) {
        bf16x8 r;
#pragma unroll
        for (int i = 0; i < 8; i++) {
          float h = fmaf(cx[nt][0], wa[ks][i],
                    fmaf(cx[nt][1], wb_[ks][i],
                    fmaf(cx[nt][2], wc_[ks][i], b1v[ks][i])));
          r[i] = f2bf(fmaxf(h, 0.f));
        }
        B2[ks] = r;
      }
      // ---- L2 (all 8 m-tiles) ----
      f32x4 acc2[8];
#pragma unroll
      for (int mt = 0; mt < 8; mt++) {
        f32x4 a = b2v[mt];
        a = __builtin_amdgcn_mfma_f32_16x16x32_bf16(A2f[mt][0], B2[0], a, 0, 0, 0);
        a = __builtin_amdgcn_mfma_f32_16x16x32_bf16(A2f[mt][1], B2[1], a, 0, 0, 0);
        acc2[mt] = a;
      }
      // ---- B3 from D2 (lane identity, relu) ----
      bf16x8 B3[4];
#pragma unroll
      for (int ks = 0; ks < 4; ks++) {
        bf16x8 r;
#pragma unroll
        for (int i = 0; i < 8; i++)
          r[i] = f2bf(fmaxf(acc2[2 * ks + (i >> 2)][i & 3], 0.f));
        B3[ks] = r;
      }
      // ---- L3 (all 8 m-tiles) + running max-pool ----
#pragma unroll
      for (int mt = 0; mt < 8; mt++) {
        f32x4 a = {0.f, 0.f, 0.f, 0.f};
        a = __builtin_amdgcn_mfma_f32_16x16x32_bf16(A3f[mt][0], B3[0], a, 0, 0, 0);
        a = __builtin_amdgcn_mfma_f32_16x16x32_bf16(A3f[mt][1], B3[1], a, 0, 0, 0);
        a = __builtin_amdgcn_mfma_f32_16x16x32_bf16(A3f[mt][2], B3[2], a, 0, 0, 0);
        a = __builtin_amdgcn_mfma_f32_16x16x32_bf16(A3f[mt][3], B3[3], a, 0, 0, 0);
#pragma unroll
        for (int r = 0; r < 4; r++) pool[mt][r] = fmaxf(pool[mt][r], a[r]);
      }
    }
  }

  // reduce over the 16 point-columns (lanes sharing the same group)
#pragma unroll
  for (int mt = 0; mt < 8; mt++)
#pragma unroll
    for (int r = 0; r < 4; r++) {
      float v = pool[mt][r];
      v = fmaxf(v, __shfl_xor(v, 1, 64));
      v = fmaxf(v, __shfl_xor(v, 2, 64));
      v = fmaxf(v, __shfl_xor(v, 4, 64));
      v = fmaxf(v, __shfl_xor(v, 8, 64));
      pool[mt][r] = v;
    }
  if (c == 0) {
#pragma unroll
    for (int mt = 0; mt < 8; mt++)
#pragma unroll
      for (int r = 0; r < 4; r++) {
        const int ch = 16 * mt + 4 * g + r;
        ymax[(size_t)frame * 128 + ch] = pool[mt][r] + eb3[ch];
      }
  }
}

// ====== fused transformer: 1 block/batch, 512 threads, in-phase W loads (R6/R11) ======
__global__ __launch_bounds__(512, 1) void xformer_kernel(
    const float* __restrict__ ymax, const int* __restrict__ fl,
    const float* __restrict__ ctok, const float* __restrict__ cpos,
    const unsigned short* __restrict__ wbf,
    const float* __restrict__ in_b, const float* __restrict__ ob,
    const float* __restrict__ l1g, const float* __restrict__ l1b,
    const float* __restrict__ f1b, const float* __restrict__ f2b,
    const float* __restrict__ l2g, const float* __restrict__ l2b,
    float* __restrict__ zbuf)
{
  __shared__ __align__(16) float ylds[64 * 128];
  __shared__ __align__(16) unsigned short ubuf[64 * 256];
  __shared__ __align__(16) unsigned short kq4[2][8][4][64][4];
  const int b = blockIdx.x, tid = threadIdx.x;
  const int w8 = tid >> 6, lane = tid & 63, c = lane & 15, g = lane >> 4;
  const int h = w8 >> 1, sub = w8 & 1;
  const int flb = fl[b];
  const float scl = 0.17677669529663687f;

  for (int it = 0; it < 16; it++) {
    int idx = it * 512 + tid;
    int t = idx >> 7, d = idx & 127;
    float v;
    if (t == 0) v = ctok[d] + cpos[d];
    else if (t <= 60) {
      int f = t - 1;
      float ym = (f < flb) ? ymax[(size_t)(b * 60 + f) * 128 + d] : 0.f;
      float dv = __expf((float)(d & ~1) * (-0.07195578416f));
      float ang = (float)f * dv;
      v = ym + ((d & 1) ? __cosf(ang) : __sinf(ang));
    } else v = 0.f;
    ylds[YI(t, d)] = v;
  }
  __syncthreads();

  for (int l = 0; l < 2; l++) {
    const unsigned short* WL = wbf + 28672 + (size_t)l * 131072;
    const bf16x8* wq  = (const bf16x8*)WL;
    const bf16x8* wo  = (const bf16x8*)(WL + 49152);
    const bf16x8* w1p = (const bf16x8*)(WL + 65536);
    const bf16x8* w2p = (const bf16x8*)(WL + 98304);
    unsigned short* vb = ubuf + 8192 + h * 2048;

    // ---------- qkv ----------
    {
      bf16x8 yB[4][4];
#pragma unroll
      for (int nt = 0; nt < 4; nt++)
#pragma unroll
        for (int ks = 0; ks < 4; ks++) {
          f32x4 lo = *(const f32x4*)&ylds[YI(16 * nt + c, 32 * ks + 4 * g)];
          f32x4 hi = *(const f32x4*)&ylds[YI(16 * nt + c, 32 * ks + 16 + 4 * g)];
          yB[nt][ks] = pack8(lo, hi);
        }
#pragma unroll
      for (int p = 0; p < 3; p++) {
        const int tq = p * 8 + w8;
        bf16x8 Af[4];
#pragma unroll
        for (int ks = 0; ks < 4; ks++) Af[ks] = wq[(tq * 4 + ks) * 64 + lane];
        f32x4 bias = *(const f32x4*)(in_b + l * 384 + p * 128 + 16 * w8 + 4 * g);
        f32x4 acc[4];
#pragma unroll
        for (int nt = 0; nt < 4; nt++) acc[nt] = bias;
#pragma unroll
        for (int ks = 0; ks < 4; ks++)
#pragma unroll
          for (int nt = 0; nt < 4; nt++)
            acc[nt] = __builtin_amdgcn_mfma_f32_16x16x32_bf16(Af[ks], yB[nt][ks], acc[nt], 0, 0, 0);
        if (p == 2) {
#pragma unroll
          for (int nt = 0; nt < 4; nt++)
            *(s16x4*)&vb[VI(16 * nt + c, 16 * sub + 4 * g)] = pack4(acc[nt]);
        } else {
#pragma unroll
          for (int nt = 0; nt < 4; nt++) {
            f32x4 sv = acc[nt];
            if (p == 0) sv = sv * scl;
            *(s16x4*)&kq4[p][w8][nt][lane][0] = pack4(sv);
          }
        }
      }
    }
    __syncthreads();

    // ---------- attention ----------
    {
      bf16x8 Ak[4], Bq2[2];
#pragma unroll
      for (int kt = 0; kt < 4; kt++) {
        s16x4 lo = *(const s16x4*)&kq4[1][2 * h][kt][lane][0];
        s16x4 hi = *(const s16x4*)&kq4[1][2 * h + 1][kt][lane][0];
        Ak[kt] = __builtin_shufflevector(lo, hi, 0, 1, 2, 3, 4, 5, 6, 7);
      }
#pragma unroll
      for (int j = 0; j < 2; j++) {
        s16x4 lo = *(const s16x4*)&kq4[0][2 * h][2 * sub + j][lane][0];
        s16x4 hi = *(const s16x4*)&kq4[0][2 * h + 1][2 * sub + j][lane][0];
        Bq2[j] = __builtin_shufflevector(lo, hi, 0, 1, 2, 3, 4, 5, 6, 7);
      }
      f32x4 St[4][2];
#pragma unroll
      for (int kt = 0; kt < 4; kt++)
#pragma unroll
        for (int j = 0; j < 2; j++) {
          f32x4 z = {0.f, 0.f, 0.f, 0.f};
          St[kt][j] = __builtin_amdgcn_mfma_f32_16x16x32_bf16(Ak[kt], Bq2[j], z, 0, 0, 0);
        }
#pragma unroll
      for (int j = 0; j < 2; j++) {
        float m = -1e30f;
#pragma unroll
        for (int kt = 0; kt < 4; kt++)
#pragma unroll
          for (int r = 0; r < 4; r++) {
            const int kp = 16 * kt + 4 * g + r;
            float s = St[kt][j][r];
            s = (kp > flb) ? -1e30f : s;
            St[kt][j][r] = s;
            m = fmaxf(m, s);
          }
        m = fmaxf(m, __shfl_xor(m, 16, 64));
        m = fmaxf(m, __shfl_xor(m, 32, 64));
        float sum = 0.f;
#pragma unroll
        for (int kt = 0; kt < 4; kt++)
#pragma unroll
          for (int r = 0; r < 4; r++) {
            float p = __expf(St[kt][j][r] - m);
            St[kt][j][r] = p;
            sum += p;
          }
        sum += __shfl_xor(sum, 16, 64);
        sum += __shfl_xor(sum, 32, 64);
        const float inv = 1.f / sum;
#pragma unroll
        for (int kt = 0; kt < 4; kt++)
#pragma unroll
          for (int r = 0; r < 4; r++) St[kt][j][r] *= inv;
      }
      bf16x8 Bp[2][2];
#pragma unroll
      for (int j = 0; j < 2; j++)
#pragma unroll
        for (int ks = 0; ks < 2; ks++) {
          bf16x8 r;
#pragma unroll
          for (int i = 0; i < 8; i++) r[i] = f2bf(St[2 * ks + (i >> 2)][j][i & 3]);
          Bp[j][ks] = r;
        }
      bf16x8 Av[2][2];
#pragma unroll
      for (int dt = 0; dt < 2; dt++)
#pragma unroll
        for (int ks = 0; ks < 2; ks++) {
          bf16x8 r;
#pragma unroll
          for (int i = 0; i < 8; i++) {
            const int kp = 32 * ks + 16 * (i >> 2) + 4 * g + (i & 3);
            r[i] = (short)vb[VI(kp, 16 * dt + c)];
          }
          Av[dt][ks] = r;
        }
#pragma unroll
      for (int dt = 0; dt < 2; dt++)
#pragma unroll
        for (int j = 0; j < 2; j++) {
          f32x4 z = {0.f, 0.f, 0.f, 0.f};
          z = __builtin_amdgcn_mfma_f32_16x16x32_bf16(Av[dt][0], Bp[j][0], z, 0, 0, 0);
          z = __builtin_amdgcn_mfma_f32_16x16x32_bf16(Av[dt][1], Bp[j][1], z, 0, 0, 0);
          *(s16x4*)&ubuf[OI(16 * (2 * sub + j) + c, 32 * h + 16 * dt + 4 * g)] = pack4(z);
        }
    }
    __syncthreads();

    // ---------- proj + residual ----------
    {
      bf16x8 Bo[4][4];
#pragma unroll
      for (int nt = 0; nt < 4; nt++)
#pragma unroll
        for (int ks = 0; ks < 4; ks++) {
          s16x4 lo = *(const s16x4*)&ubuf[OI(16 * nt + c, 32 * ks + 4 * g)];
          s16x4 hi = *(const s16x4*)&ubuf[OI(16 * nt + c, 32 * ks + 16 + 4 * g)];
          Bo[nt][ks] = __builtin_shufflevector(lo, hi, 0, 1, 2, 3, 4, 5, 6, 7);
        }
      const int j0 = 16 * w8;
      bf16x8 Af[4];
#pragma unroll
      for (int ks = 0; ks < 4; ks++) Af[ks] = wo[(w8 * 4 + ks) * 64 + lane];
      f32x4 bias = *(const f32x4*)(ob + l * 128 + j0 + 4 * g);
      f32x4 acc[4];
#pragma unroll
      for (int nt = 0; nt < 4; nt++) acc[nt] = bias;
#pragma unroll
      for (int ks = 0; ks < 4; ks++)
#pragma unroll
        for (int nt = 0; nt < 4; nt++)
          acc[nt] = __builtin_amdgcn_mfma_f32_16x16x32_bf16(Af[ks], Bo[nt][ks], acc[nt], 0, 0, 0);
#pragma unroll
      for (int nt = 0; nt < 4; nt++) {
        float* yp = &ylds[YI(16 * nt + c, j0 + 4 * g)];
        *(f32x4*)yp = *(const f32x4*)yp + acc[nt];
      }
    }
    __syncthreads();
    // ---------- LN1 ----------
    {
      const int t = 8 * w8 + (lane >> 3);
      const int s = lane & 7;
      f32x4 vv[4];
      float s1 = 0.f, s2 = 0.f;
#pragma unroll
      for (int k = 0; k < 4; k++) {
        vv[k] = *(const f32x4*)&ylds[YI(t, s * 16 + 4 * k)];
#pragma unroll
        for (int r = 0; r < 4; r++) { s1 += vv[k][r]; s2 = fmaf(vv[k][r], vv[k][r], s2); }
      }
      s1 += __shfl_xor(s1, 1, 64); s1 += __shfl_xor(s1, 2, 64); s1 += __shfl_xor(s1, 4, 64);
      s2 += __shfl_xor(s2, 1, 64); s2 += __shfl_xor(s2, 2, 64); s2 += __shfl_xor(s2, 4, 64);
      const float mean = s1 * 0.0078125f;
      const float var  = s2 * 0.0078125f - mean * mean;
      const float inv  = rsqrtf(var + EPSV);
#pragma unroll
      for (int k = 0; k < 4; k++) {
        f32x4 gg = *(const f32x4*)(l1g + l * 128 + s * 16 + 4 * k);
        f32x4 bb = *(const f32x4*)(l1b + l * 128 + s * 16 + 4 * k);
        f32x4 o;
#pragma unroll
        for (int r = 0; r < 4; r++) o[r] = (vv[k][r] - mean) * inv * gg[r] + bb[r];
        *(f32x4*)&ylds[YI(t, s * 16 + 4 * k)] = o;
      }
    }
    __syncthreads();

    // ---------- ff1 (relu) ----------
    {
      bf16x8 yB[4][4];
#pragma unroll
      for (int nt = 0; nt < 4; nt++)
#pragma unroll
        for (int ks = 0; ks < 4; ks++) {
          f32x4 lo = *(const f32x4*)&ylds[YI(16 * nt + c, 32 * ks + 4 * g)];
          f32x4 hi = *(const f32x4*)&ylds[YI(16 * nt + c, 32 * ks + 16 + 4 * g)];
          yB[nt][ks] = pack8(lo, hi);
        }
#pragma unroll
      for (int half = 0; half < 2; half++) {
        const int t16 = 8 * half + w8;
        bf16x8 Af[4];
#pragma unroll
        for (int ks = 0; ks < 4; ks++) Af[ks] = w1p[(t16 * 4 + ks) * 64 + lane];
        f32x4 bias = *(const f32x4*)(f1b + l * 256 + 16 * t16 + 4 * g);
        f32x4 acc[4];
#pragma unroll
        for (int nt = 0; nt < 4; nt++) acc[nt] = bias;
#pragma unroll
        for (int ks = 0; ks < 4; ks++)
#pragma unroll
          for (int nt = 0; nt < 4; nt++)
            acc[nt] = __builtin_amdgcn_mfma_f32_16x16x32_bf16(Af[ks], yB[nt][ks], acc[nt], 0, 0, 0);
#pragma unroll
        for (int nt = 0; nt < 4; nt++) {
          f32x4 rl;
#pragma unroll
          for (int r = 0; r < 4; r++) rl[r] = fmaxf(acc[nt][r], 0.f);
          *(s16x4*)&ubuf[FI(16 * nt + c, 16 * t16 + 4 * g)] = pack4(rl);
        }
      }
    }
    __syncthreads();
    // ---------- ff2 + residual ----------
    {
      f32x4 acc[4];
      f32x4 bias = *(const f32x4*)(f2b + l * 128 + 16 * w8 + 4 * g);
#pragma unroll
      for (int nt = 0; nt < 4; nt++) acc[nt] = bias;
#pragma unroll
      for (int ks = 0; ks < 8; ks++) {
        bf16x8 Af = w2p[(w8 * 8 + ks) * 64 + lane];
        bf16x8 Bf[4];
#pragma unroll
        for (int nt = 0; nt < 4; nt++) {
          s16x4 lo = *(const s16x4*)&ubuf[FI(16 * nt + c, 32 * ks + 4 * g)];
          s16x4 hi = *(const s16x4*)&ubuf[FI(16 * nt + c, 32 * ks + 16 + 4 * g)];
          Bf[nt] = __builtin_shufflevector(lo, hi, 0, 1, 2, 3, 4, 5, 6, 7);
        }
#pragma unroll
        for (int nt = 0; nt < 4; nt++)
          acc[nt] = __builtin_amdgcn_mfma_f32_16x16x32_bf16(Af, Bf[nt], acc[nt], 0, 0, 0);
      }
#pragma unroll
      for (int nt = 0; nt < 4; nt++) {
        float* yp = &ylds[YI(16 * nt + c, 16 * w8 + 4 * g)];
        *(f32x4*)yp = *(const f32x4*)yp + acc[nt];
      }
    }
    __syncthreads();
    // ---------- LN2 ----------
    {
      const int t = 8 * w8 + (lane >> 3);
      const int s = lane & 7;
      f32x4 vv[4];
      float s1 = 0.f, s2 = 0.f;
#pragma unroll
      for (int k = 0; k < 4; k++) {
        vv[k] = *(const f32x4*)&ylds[YI(t, s * 16 + 4 * k)];
#pragma unroll
        for (int r = 0; r < 4; r++) { s1 += vv[k][r]; s2 = fmaf(vv[k][r], vv[k][r], s2); }
      }
      s1 += __shfl_xor(s1, 1, 64); s1 += __shfl_xor(s1, 2, 64); s1 += __shfl_xor(s1, 4, 64);
      s2 += __shfl_xor(s2, 1, 64); s2 += __shfl_xor(s2, 2, 64); s2 += __shfl_xor(s2, 4, 64);
      const float mean = s1 * 0.0078125f;
      const float var  = s2 * 0.0078125f - mean * mean;
      const float inv  = rsqrtf(var + EPSV);
#pragma unroll
      for (int k = 0; k < 4; k++) {
        f32x4 gg = *(const f32x4*)(l2g + l * 128 + s * 16 + 4 * k);
        f32x4 bb = *(const f32x4*)(l2b + l * 128 + s * 16 + 4 * k);
        f32x4 o;
#pragma unroll
        for (int r = 0; r < 4; r++) o[r] = (vv[k][r] - mean) * inv * gg[r] + bb[r];
        *(f32x4*)&ylds[YI(t, s * 16 + 4 * k)] = o;
      }
    }
    __syncthreads();
  }

  // classifier inputs, TRANSPOSED: zbuf[ch][b]
  if (tid < 256) {
    const int d = tid;
    float v = (d < 128) ? ylds[YI(0, d)] : ylds[YI(flb, d - 128)];
    zbuf[d * 16 + b] = v;
  }
}

// ====== head: MFMA hi/lo (≈fp32), transposed D[ch][batch], live BN (R6) ======
__device__ __forceinline__ void buildB(const float* src, int ks, int g, int c,
                                       bf16x8& bh, bf16x8& bl){
#pragma unroll
  for (int i = 0; i < 8; i++) {
    int k = 32 * ks + 16 * (i >> 2) + 4 * g + (i & 3);
    float v = src[k * 16 + c];
    short hv = f2bf(v);
    bh[i] = hv; bl[i] = f2bf(v - bf2f(hv));
  }
}
__device__ __forceinline__ void bn_lrelu_store(f32x4 acc, int ch0, int c,
    const float* __restrict__ gg, const float* __restrict__ bb, float* dst){
#pragma unroll
  for (int r = 0; r < 4; r++) {
    float v = acc[r];
    float s1 = v, s2 = v * v;
    s1 += __shfl_xor(s1, 1, 64); s2 += __shfl_xor(s2, 1, 64);
    s1 += __shfl_xor(s1, 2, 64); s2 += __shfl_xor(s2, 2, 64);
    s1 += __shfl_xor(s1, 4, 64); s2 += __shfl_xor(s2, 4, 64);
    s1 += __shfl_xor(s1, 8, 64); s2 += __shfl_xor(s2, 8, 64);
    const float m = s1 * (1.f / 16.f);
    const float var = s2 * (1.f / 16.f) - m * m;
    const float scl = gg[ch0 + r] / sqrtf(var + EPSV);
    const float sh = bb[ch0 + r] - m * scl;
    float o = v * scl + sh;
    o = (o > 0.f) ? o : 0.2f * o;
    dst[(ch0 + r) * 16 + c] = o;
  }
}

__global__ __launch_bounds__(256, 1) void head_kernel(
    const float* __restrict__ zt, const unsigned short* __restrict__ wbf,
    const float* __restrict__ fc1b, const float* __restrict__ bn1g, const float* __restrict__ bn1b,
    const float* __restrict__ fc15b, const float* __restrict__ bn15g, const float* __restrict__ bn15b,
    const float* __restrict__ fc2b, const float* __restrict__ bn2g, const float* __restrict__ bn2b,
    const float* __restrict__ fcb, float* __restrict__ out)
{
  __shared__ float zs[256 * 16];
  __shared__ float t1s[128 * 16];
  __shared__ float t15s[64 * 16];
  __shared__ float t2s[32 * 16];
  const int tid = threadIdx.x, lane = tid & 63, wv = tid >> 6;
  const int c = lane & 15, g = lane >> 4;
  const bf16x8* wf = (const bf16x8*)wbf;

  for (int idx = tid; idx < 4096; idx += 256) zs[idx] = zt[idx];
  __syncthreads();

  {
    f32x4 acc[2];
#pragma unroll
    for (int j = 0; j < 2; j++) {
      const int ch0 = 16 * (2 * wv + j) + 4 * g;
      f32x4 a;
#pragma unroll
      for (int r = 0; r < 4; r++) a[r] = fc1b[ch0 + r];
      acc[j] = a;
    }
#pragma unroll
    for (int ks = 0; ks < 8; ks++) {
      bf16x8 bh, bl; buildB(zs, ks, g, c, bh, bl);
#pragma unroll
      for (int j = 0; j < 2; j++) {
        const int mt = 2 * wv + j;
        bf16x8 Ah = wf[(568 + mt * 8 + ks) * 64 + lane];
        bf16x8 Al = wf[(632 + mt * 8 + ks) * 64 + lane];
        acc[j] = __builtin_amdgcn_mfma_f32_16x16x32_bf16(Ah, bh, acc[j], 0, 0, 0);
        acc[j] = __builtin_amdgcn_mfma_f32_16x16x32_bf16(Ah, bl, acc[j], 0, 0, 0);
        acc[j] = __builtin_amdgcn_mfma_f32_16x16x32_bf16(Al, bh, acc[j], 0, 0, 0);
      }
    }
#pragma unroll
    for (int j = 0; j < 2; j++)
      bn_lrelu_store(acc[j], 16 * (2 * wv + j) + 4 * g, c, bn1g, bn1b, t1s);
  }
  __syncthreads();

  {
    const int ch0 = 16 * wv + 4 * g;
    f32x4 a;
#pragma unroll
    for (int r = 0; r < 4; r++) a[r] = fc15b[ch0 + r];
#pragma unroll
    for (int ks = 0; ks < 4; ks++) {
      bf16x8 bh, bl; buildB(t1s, ks, g, c, bh, bl);
      bf16x8 Ah = wf[(696 + wv * 4 + ks) * 64 + lane];
      bf16x8 Al = wf[(712 + wv * 4 + ks) * 64 + lane];
      a = __builtin_amdgcn_mfma_f32_16x16x32_bf16(Ah, bh, a, 0, 0, 0);
      a = __builtin_amdgcn_mfma_f32_16x16x32_bf16(Ah, bl, a, 0, 0, 0);
      a = __builtin_amdgcn_mfma_f32_16x16x32_bf16(Al, bh, a, 0, 0, 0);
    }
    bn_lrelu_store(a, ch0, c, bn15g, bn15b, t15s);
  }
  __syncthreads();

  if (wv < 2) {
    const int ch0 = 16 * wv + 4 * g;
    f32x4 a;
#pragma unroll
    for (int r = 0; r < 4; r++) a[r] = fc2b[ch0 + r];
#pragma unroll
    for (int ks = 0; ks < 2; ks++) {
      bf16x8 bh, bl; buildB(t15s, ks, g, c, bh, bl);
      bf16x8 Ah = wf[(728 + wv * 2 + ks) * 64 + lane];
      bf16x8 Al = wf[(732 + wv * 2 + ks) * 64 + lane];
      a = __builtin_amdgcn_mfma_f32_16x16x32_bf16(Ah, bh, a, 0, 0, 0);
      a = __builtin_amdgcn_mfma_f32_16x16x32_bf16(Ah, bl, a, 0, 0, 0);
      a = __builtin_amdgcn_mfma_f32_16x16x32_bf16(Al, bh, a, 0, 0, 0);
    }
    bn_lrelu_store(a, ch0, c, bn2g, bn2b, t2s);
  }
  __syncthreads();

  if (wv < 2) {
    f32x4 a;
#pragma unroll
    for (int r = 0; r < 4; r++) {
      const int ch = 16 * wv + 4 * g + r;
      a[r] = (ch < 27) ? fcb[ch] : 0.f;
    }
    bf16x8 bh, bl; buildB(t2s, 0, g, c, bh, bl);
    bf16x8 Ah = wf[(736 + wv) * 64 + lane];
    bf16x8 Al = wf[(738 + wv) * 64 + lane];
    a = __builtin_amdgcn_mfma_f32_16x16x32_bf16(Ah, bh, a, 0, 0, 0);
    a = __builtin_amdgcn_mfma_f32_16x16x32_bf16(Ah, bl, a, 0, 0, 0);
    a = __builtin_amdgcn_mfma_f32_16x16x32_bf16(Al, bh, a, 0, 0, 0);
#pragma unroll
    for (int r = 0; r < 4; r++) {
      const int ch = 16 * wv + 4 * g + r;
      if (ch < 27) out[c * 27 + ch] = a[r];
    }
  }
}

extern "C" void kernel_launch(void* const* d_in, const int* in_sizes, int n_in,
                              void* d_out, int out_size, void* d_ws, size_t ws_size,
                              hipStream_t stream)
{
  const float* x    = (const float*)d_in[0];
  const int*   fl   = (const int*)d_in[1];
  const float* ew1  = (const float*)d_in[2];  const float* eb1 = (const float*)d_in[3];
  const float* ew2  = (const float*)d_in[4];  const float* eb2 = (const float*)d_in[5];
  const float* ew3  = (const float*)d_in[6];  const float* eb3 = (const float*)d_in[7];
  const float* ctok = (const float*)d_in[8];  const float* cpos = (const float*)d_in[9];
  const float* in_w = (const float*)d_in[10]; const float* in_b = (const float*)d_in[11];
  const float* ow   = (const float*)d_in[12]; const float* ob   = (const float*)d_in[13];
  const float* l1g  = (const float*)d_in[14]; const float* l1b  = (const float*)d_in[15];
  const float* f1w  = (const float*)d_in[16]; const float* f1b  = (const float*)d_in[17];
  const float* f2w  = (const float*)d_in[18]; const float* f2b  = (const float*)d_in[19];
  const float* l2g  = (const float*)d_in[20]; const float* l2b  = (const float*)d_in[21];
  const float* fc1w = (const float*)d_in[22]; const float* fc1b = (const float*)d_in[23];
  const float* bn1g = (const float*)d_in[24]; const float* bn1b = (const float*)d_in[25];
  const float* fc15w= (const float*)d_in[26]; const float* fc15b= (const float*)d_in[27];
  const float* bn15g= (const float*)d_in[28]; const float* bn15b= (const float*)d_in[29];
  const float* fc2w = (const float*)d_in[30]; const float* fc2b = (const float*)d_in[31];
  const float* bn2g = (const float*)d_in[32]; const float* bn2b = (const float*)d_in[33];
  const float* fcw  = (const float*)d_in[34]; const float* fcb  = (const float*)d_in[35];
  float* out = (float*)d_out;

  char* w = (char*)d_ws;
  float* ymax = (float*)w;                                   // 491520 B
  float* zbuf = (float*)(w + 491520);                        // 16384 B (transposed [ch][b])
  unsigned short* wbf = (unsigned short*)(w + 507904);       // 740 frags * 1024 B

  prep_kernel<<<1480, 256, 0, stream>>>(ew1, eb1, ew2, ew3, in_w, ow, f1w, f2w,
                                        fc1w, fc15w, fc2w, fcw, wbf);
  enc_kernel<<<240, 256, 0, stream>>>(x, ew1, eb1, eb2, eb3, wbf, ymax);
  xformer_kernel<<<16, 512, 0, stream>>>(ymax, fl, ctok, cpos, wbf, in_b, ob,
                                         l1g, l1b, f1b, f2b, l2g, l2b, zbuf);
  head_kernel<<<1, 256, 0, stream>>>(zbuf, wbf, fc1b, bn1g, bn1b,
                                     fc15b, bn15g, bn15b, fc2b, bn2g, bn2b, fcb, out);
}